// Round 2
// baseline (259.243 us; speedup 1.0000x reference)
//
#include <hip/hip_runtime.h>
#include <math.h>

#define BB 16
#define HH 512
#define WW 512
#define CC 4

// ---------------------------------------------------------------------------
// Kernel 1: column scan of logistic(defgrad.y) -> ys, plus planar
// logistic(defgrad.x) -> dgx (when workspace permits).
//   grid: BB * (WW/32) = 256 blocks; block: 1024 threads = 32 segs x 32 cols.
//   H walked in 4 chunks of 128 rows. All global accesses are full-line
//   bursts: loads 2 rows x 256B (float2), stores 2 rows x 128B.
// ---------------------------------------------------------------------------
#define CS_COLS    32
#define CS_THREADS 1024
#define CS_SEGS    (CS_THREADS / CS_COLS)   // 32
#define CS_CHUNK   128
#define CS_SEGH    (CS_CHUNK / CS_SEGS)     // 4
#define CS_NCHUNK  (HH / CS_CHUNK)          // 4

__global__ __launch_bounds__(CS_THREADS)
void colscan_kernel(const float2* __restrict__ defgrad,
                    float* __restrict__ ys, int ys_stride,
                    float* __restrict__ dgx) {
    const int wt  = blockIdx.x % (WW / CS_COLS);
    const int b   = blockIdx.x / (WW / CS_COLS);
    const int tid = threadIdx.x;
    const int col = tid & (CS_COLS - 1);
    const int seg = tid >> 5;               // 0..31 (row base in load phase)

    __shared__ float lds[CS_CHUNK][CS_COLS + 1];  // (r+col)%32 -> 2-way, free
    __shared__ float part[CS_SEGS][CS_COLS];
    __shared__ float carry[2][CS_COLS];

    if (tid < CS_COLS) carry[0][tid] = 0.f;

    const size_t ibase = (size_t)b * HH * WW + wt * CS_COLS;  // + row*WW + col

    for (int c = 0; c < CS_NCHUNK; ++c) {
        // ---- load float2, logistic both channels, dgx out, .y into LDS
#pragma unroll
        for (int k = 0; k < 4; ++k) {
            const int r    = seg + k * 32;            // 0..127
            const int grow = c * CS_CHUNK + r;
            const size_t gi = ibase + (size_t)grow * WW + col;
            float2 v = defgrad[gi];
            float lx = 2.0f / (1.0f + expf(-v.x));
            float ly = 2.0f / (1.0f + expf(-v.y));
            if (dgx) dgx[gi] = lx;
            lds[r][col] = ly;
        }
        __syncthreads();

        // ---- per-segment serial sums (kept in regs)
        float vals[CS_SEGH];
        float s = 0.f;
#pragma unroll
        for (int i = 0; i < CS_SEGH; ++i) {
            vals[i] = lds[seg * CS_SEGH + i][col];
            s += vals[i];
        }
        part[seg][col] = s;
        const float cold = carry[c & 1][col];
        __syncthreads();

        // ---- exclusive segment prefix + chunk total (broadcast reads)
        float run = cold, tot = cold;
#pragma unroll
        for (int j = 0; j < CS_SEGS; ++j) {
            float v = part[j][col];
            tot += v;
            if (j < seg) run += v;
        }
        if (seg == 0) carry[(c + 1) & 1][col] = tot;

        // ---- write inclusive scan values (2 rows x 128B per instr)
        const size_t gidx0 =
            (size_t)(b * HH + c * CS_CHUNK + seg * CS_SEGH) * WW + wt * CS_COLS + col;
#pragma unroll
        for (int i = 0; i < CS_SEGH; ++i) {
            run += vals[i];
            ys[(gidx0 + (size_t)i * WW) * (size_t)ys_stride] = run;
        }
        __syncthreads();
    }
}

// ---------------------------------------------------------------------------
// Kernel 2: per-row fused — x_s row scan + residual affine + bilinear sample.
// v3: consumes planar dgx/ys when available (no interleaved defgrad fetch,
// no expf); __launch_bounds__(512,4) relaxes VGPR cap to ~128 so all 16
// bilinear gathers issue concurrently (v2's VGPR=32 serialized them into 4
// dependent epochs); 2 blocks/CU also shrinks the concurrent im footprint
// per XCD to ~2.5 MB -> fits the 4 MB L2.
//   grid: BB*HH/4 = 2048 blocks; block: 512 threads (one per column).
// ---------------------------------------------------------------------------
#define RS_ROWS 4

__global__ __launch_bounds__(512, 4)
void rowscan_sample_kernel(const float4* __restrict__ im4,
                           const float2* __restrict__ defgrad,
                           const float*  __restrict__ affine,
                           const float*  __restrict__ ys, int ys_stride,
                           const float*  __restrict__ dgxp,
                           float4* __restrict__ out4,
                           float*  __restrict__ grid3) {
    // bijective XCD swizzle: 2048 % 8 == 0, consecutive logical ids per XCD
    const int nwg = BB * (HH / RS_ROWS);
    const int cpx = nwg / 8;
    const int l   = (blockIdx.x & 7) * cpx + (blockIdx.x >> 3);
    const int hb  = l % (HH / RS_ROWS);
    const int b   = l / (HH / RS_ROWS);
    const int h0  = hb * RS_ROWS;

    const int w    = threadIdx.x;          // 0..511 column
    const int lane = w & 63;
    const int wv   = w >> 6;               // 0..7

    const size_t imgbase  = (size_t)b * HH * WW;
    const size_t rowbase0 = imgbase + (size_t)h0 * WW + w;

    // ---- early independent loads: dgx (planar or via logistic) and ys
    float dgxv[RS_ROWS], ysv[RS_ROWS];
    if (dgxp) {
#pragma unroll
        for (int r = 0; r < RS_ROWS; ++r) {
            const size_t pix = rowbase0 + (size_t)r * WW;
            dgxv[r] = dgxp[pix];
            ysv[r]  = ys[pix];
        }
    } else {
#pragma unroll
        for (int r = 0; r < RS_ROWS; ++r) {
            const size_t pix = rowbase0 + (size_t)r * WW;
            dgxv[r] = defgrad[pix].x;
            ysv[r]  = ys[pix * (size_t)ys_stride];
        }
#pragma unroll
        for (int r = 0; r < RS_ROWS; ++r)
            dgxv[r] = 2.0f / (1.0f + expf(-dgxv[r]));
    }

    // ---- 4 simultaneous inclusive block scans (wave scan + LDS combine)
    float x0 = dgxv[0], x1 = dgxv[1], x2 = dgxv[2], x3 = dgxv[3];
#pragma unroll
    for (int off = 1; off < 64; off <<= 1) {
        float n0 = __shfl_up(x0, off, 64);
        float n1 = __shfl_up(x1, off, 64);
        float n2 = __shfl_up(x2, off, 64);
        float n3 = __shfl_up(x3, off, 64);
        if (lane >= off) { x0 += n0; x1 += n1; x2 += n2; x3 += n3; }
    }
    __shared__ float wsum[8][RS_ROWS];
    if (lane == 63) {
        wsum[wv][0] = x0; wsum[wv][1] = x1; wsum[wv][2] = x2; wsum[wv][3] = x3;
    }
    __syncthreads();
    float p0 = 0.f, p1 = 0.f, p2 = 0.f, p3 = 0.f;
    for (int j = 0; j < wv; ++j) {
        p0 += wsum[j][0]; p1 += wsum[j][1]; p2 += wsum[j][2]; p3 += wsum[j][3];
    }
    float xs[RS_ROWS] = { x0 + p0, x1 + p1, x2 + p2, x3 + p3 };

    // ---- residual affine (A = affine + I), uniform per block -> SGPRs
    const float* Ab = affine + b * 9;
    const float a00 = Ab[0] + 1.f, a01 = Ab[1], a02 = Ab[2];
    const float a10 = Ab[3], a11 = Ab[4] + 1.f, a12 = Ab[5];
    const float a20 = Ab[6], a21 = Ab[7], a22 = Ab[8] + 1.f;

    // ---- phase 1: all addresses + weights
    float xg[RS_ROWS], yg[RS_ROWS], wgv[RS_ROWS];
    int   offA[RS_ROWS], offB[RS_ROWS], offC[RS_ROWS], offD[RS_ROWS];
    float wa[RS_ROWS], wb[RS_ROWS], wc[RS_ROWS], wd[RS_ROWS];
#pragma unroll
    for (int r = 0; r < RS_ROWS; ++r) {
        xg[r]  = a00 * xs[r] + a01 * ysv[r] + a02;
        yg[r]  = a10 * xs[r] + a11 * ysv[r] + a12;
        wgv[r] = a20 * xs[r] + a21 * ysv[r] + a22;

        const int ix = (int)floorf(xg[r]);
        const int iy = (int)floorf(yg[r]);
        const int cx0 = min(max(ix,     0), WW - 1);
        const int cx1 = min(max(ix + 1, 0), WW - 1);
        const int cy0 = min(max(iy,     0), HH - 1);
        const int cy1 = min(max(iy + 1, 0), HH - 1);
        const float x0f = (float)cx0, x1f = (float)cx1;
        const float y0f = (float)cy0, y1f = (float)cy1;
        wa[r] = (x1f - xg[r]) * (y1f - yg[r]);
        wb[r] = (x1f - xg[r]) * (yg[r] - y0f);
        wc[r] = (xg[r] - x0f) * (y1f - yg[r]);
        wd[r] = (xg[r] - x0f) * (yg[r] - y0f);
        offA[r] = cy0 * WW + cx0;
        offB[r] = cy1 * WW + cx0;
        offC[r] = cy0 * WW + cx1;
        offD[r] = cy1 * WW + cx1;
    }

    // ---- phase 2: issue all 16 gathers concurrently
    float4 Ia[RS_ROWS], Ib[RS_ROWS], Ic[RS_ROWS], Id[RS_ROWS];
#pragma unroll
    for (int r = 0; r < RS_ROWS; ++r) {
        Ia[r] = im4[imgbase + (size_t)offA[r]];
        Ib[r] = im4[imgbase + (size_t)offB[r]];
        Ic[r] = im4[imgbase + (size_t)offC[r]];
        Id[r] = im4[imgbase + (size_t)offD[r]];
    }

    // ---- phase 3: blend + stores
#pragma unroll
    for (int r = 0; r < RS_ROWS; ++r) {
        const size_t pix = rowbase0 + (size_t)r * WW;
        float4 o;
        o.x = wa[r] * Ia[r].x + wb[r] * Ib[r].x + wc[r] * Ic[r].x + wd[r] * Id[r].x;
        o.y = wa[r] * Ia[r].y + wb[r] * Ib[r].y + wc[r] * Ic[r].y + wd[r] * Id[r].y;
        o.z = wa[r] * Ia[r].z + wb[r] * Ib[r].z + wc[r] * Ic[r].z + wd[r] * Id[r].z;
        o.w = wa[r] * Ia[r].w + wb[r] * Ib[r].w + wc[r] * Ic[r].w + wd[r] * Id[r].w;
        out4[pix] = o;

        // grid3 (thread owns grid3[3*pix .. 3*pix+2]; fallback ysv already read)
        grid3[pix * 3 + 0] = xg[r];
        grid3[pix * 3 + 1] = yg[r];
        grid3[pix * 3 + 2] = wgv[r];
    }
}

extern "C" void kernel_launch(void* const* d_in, const int* in_sizes, int n_in,
                              void* d_out, int out_size, void* d_ws, size_t ws_size,
                              hipStream_t stream) {
    const float* im      = (const float*)d_in[0];
    const float* defgrad = (const float*)d_in[1];
    const float* affine  = (const float*)d_in[2];

    float* out   = (float*)d_out;
    float* grid3 = out + (size_t)BB * HH * WW * CC;

    const size_t plane_elems = (size_t)BB * HH * WW;
    const size_t plane_bytes = plane_elems * sizeof(float);

    float* ysp;
    int    ys_stride;
    float* dgxp = nullptr;
    if (ws_size >= 2 * plane_bytes) {      // planar ys + planar dgx (preferred)
        ysp = (float*)d_ws;
        ys_stride = 1;
        dgxp = (float*)d_ws + plane_elems;
    } else if (ws_size >= plane_bytes) {   // planar ys only
        ysp = (float*)d_ws;
        ys_stride = 1;
    } else {                               // stash in grid3[...,1] slot (race-free)
        ysp = grid3 + 1;
        ys_stride = 3;
    }

    colscan_kernel<<<BB * (WW / CS_COLS), CS_THREADS, 0, stream>>>(
        (const float2*)defgrad, ysp, ys_stride, dgxp);

    rowscan_sample_kernel<<<BB * (HH / RS_ROWS), 512, 0, stream>>>(
        (const float4*)im, (const float2*)defgrad, affine,
        ysp, ys_stride, dgxp, (float4*)out, grid3);
}